// Round 7
// baseline (195.051 us; speedup 1.0000x reference)
//
#include <hip/hip_runtime.h>
#include <hip/hip_bf16.h>

#define DEV static __device__ __forceinline__

typedef __attribute__((ext_vector_type(8))) short bf16x8;          // 8 bf16 (4 VGPRs)
typedef __attribute__((ext_vector_type(8))) unsigned short u16x8;  // raw 16B chunk
typedef __attribute__((ext_vector_type(4))) float f32x4;

constexpr int Bn = 8, Tn = 2048, DMn = 1024, DKn = 128;

DEV unsigned short f2bf(float f) {
  union { float f; unsigned u; } c; c.f = f;
  unsigned u = c.u;
  unsigned r = (u + 0x7fffu + ((u >> 16) & 1u)) >> 16;  // RNE
  return (unsigned short)r;
}

DEV void gload_lds16(const void* g, void* l) {
  __builtin_amdgcn_global_load_lds(
      (const __attribute__((address_space(1))) void*)g,
      (__attribute__((address_space(3))) void*)l, 16, 0, 0);
}

// ---------------- fp32 -> bf16 convert, weights only ----------------
__global__ void cvt_w(const float* __restrict__ wq, const float* __restrict__ wk,
                      const float* __restrict__ wv, unsigned short* __restrict__ Wb) {
  const int i = blockIdx.x * 256 + threadIdx.x;
  const int w = i >> 15;
  const int off = i & 32767;
  const float* src = (w == 0) ? wq : (w == 1) ? wk : wv;
  float4 v = reinterpret_cast<const float4*>(src)[off];
  ushort4 o;
  o.x = f2bf(v.x); o.y = f2bf(v.y); o.z = f2bf(v.z); o.w = f2bf(v.w);
  reinterpret_cast<ushort4*>(Wb + (size_t)w * 131072)[off] = o;
}

// ---------------- fused QKV projection, 2-phase pipelined ----------------
// C[16384][384] = X(fp32, cvt in staging) x W3^T. M-tile 64, grid 256 (1/CU),
// 8 waves (2m x 4n). A+B double-buffered; per K-step: issue stage(t+1) ->
// compute(t) -> ds_write A(t+1) -> s_waitcnt vmcnt(0) lgkmcnt(0) -> s_barrier.
// Stage latency hides under compute (T3-minimum). Source-side XOR swizzle (T2).
__global__ __launch_bounds__(512, 2) void qkv_proj(
    const float* __restrict__ X,            // [16384][1024] fp32
    const unsigned short* __restrict__ W3,  // [384][1024] bf16
    unsigned short* __restrict__ Q,         // [16384][128]
    unsigned short* __restrict__ K,         // [16384][128]
    unsigned short* __restrict__ VT) {      // [8][128][2048]
  __shared__ __align__(16) unsigned short Al[2][64 * 64];    // 16 KB
  __shared__ __align__(16) unsigned short Bl[2][384 * 64];   // 96 KB
  const int m0 = blockIdx.x * 64;
  const int tid = threadIdx.x;
  const int lane = tid & 63;
  const int wid = tid >> 6;
  const int wm = wid >> 2;   // 0..1
  const int wn = wid & 3;    // 0..3

  f32x4 acc[2][6] = {};

  const int arow = tid >> 3;
  const int ag8 = tid & 7;
  const float4* x4 = reinterpret_cast<const float4*>(X + (size_t)(m0 + arow) * DMn);

  // B-stage: tile t (K-cols t*64..+64) into Bl[c], 6 chunks/thread, src-swizzled
  auto stageB = [&](int t, int c) {
#pragma unroll
    for (int it = 0; it < 6; ++it) {
      const int chbase = it * 512 + (tid & ~63);
      const int ch = chbase + lane;
      const int row = ch >> 3;                 // 0..383
      const int sc8 = (ch & 7) ^ (row & 7);    // pre-swizzled source granule
      gload_lds16(&W3[(size_t)row * DMn + t * 64 + sc8 * 8], &Bl[c][chbase * 8]);
    }
  };

  float4 u = x4[ag8 * 2];
  float4 v = x4[ag8 * 2 + 1];
  stageB(0, 0);
  {
    u16x8 aw;
    aw[0] = f2bf(u.x); aw[1] = f2bf(u.y); aw[2] = f2bf(u.z); aw[3] = f2bf(u.w);
    aw[4] = f2bf(v.x); aw[5] = f2bf(v.y); aw[6] = f2bf(v.z); aw[7] = f2bf(v.w);
    *reinterpret_cast<u16x8*>(&Al[0][arow * 64 + ((ag8 ^ (arow & 7)) << 3)]) = aw;
  }
  asm volatile("s_waitcnt vmcnt(0) lgkmcnt(0)" ::: "memory");
  __builtin_amdgcn_sched_barrier(0);
  __builtin_amdgcn_s_barrier();

  for (int t = 0; t < 16; ++t) {
    const int c = t & 1;
    if (t < 15) {
      u = x4[(t + 1) * 16 + ag8 * 2];          // issue A(t+1) fp32 loads
      v = x4[(t + 1) * 16 + ag8 * 2 + 1];
      stageB(t + 1, c ^ 1);                    // issue B(t+1) -> other buffer
    }
    // compute tile t from Al[c], Bl[c]
#pragma unroll
    for (int kk = 0; kk < 2; ++kk) {
      const int lrow = lane & 15;
      const int gr = kk * 4 + (lane >> 4);
      bf16x8 af[2], bfr[6];
#pragma unroll
      for (int mf = 0; mf < 2; ++mf) {
        const int row = wm * 32 + mf * 16 + lrow;
        af[mf] = *reinterpret_cast<const bf16x8*>(&Al[c][row * 64 + ((gr ^ (row & 7)) << 3)]);
      }
#pragma unroll
      for (int nf = 0; nf < 6; ++nf) {
        const int row = wn * 96 + nf * 16 + lrow;
        bfr[nf] = *reinterpret_cast<const bf16x8*>(&Bl[c][row * 64 + ((gr ^ (row & 7)) << 3)]);
      }
#pragma unroll
      for (int mf = 0; mf < 2; ++mf)
#pragma unroll
        for (int nf = 0; nf < 6; ++nf)
          acc[mf][nf] = __builtin_amdgcn_mfma_f32_16x16x32_bf16(af[mf], bfr[nf], acc[mf][nf], 0, 0, 0);
    }
    if (t < 15) {  // A(t+1) regs have landed under compute; write to other buffer
      u16x8 aw;
      aw[0] = f2bf(u.x); aw[1] = f2bf(u.y); aw[2] = f2bf(u.z); aw[3] = f2bf(u.w);
      aw[4] = f2bf(v.x); aw[5] = f2bf(v.y); aw[6] = f2bf(v.z); aw[7] = f2bf(v.w);
      *reinterpret_cast<u16x8*>(&Al[c ^ 1][arow * 64 + ((ag8 ^ (arow & 7)) << 3)]) = aw;
    }
    asm volatile("s_waitcnt vmcnt(0) lgkmcnt(0)" ::: "memory");
    __builtin_amdgcn_sched_barrier(0);
    __builtin_amdgcn_s_barrier();
  }

  // epilogue: D layout col=lane&15, row=(lane>>4)*4+r  [measured m89]
  unsigned short (*Vt_l)[72] = reinterpret_cast<unsigned short(*)[72]>(&Bl[0][0]);  // [128][72]
  const int bidx = m0 >> 11;
  const int mb = m0 & 2047;
#pragma unroll
  for (int mf = 0; mf < 2; ++mf)
#pragma unroll
    for (int nf = 0; nf < 6; ++nf) {
      const int n = wn * 96 + nf * 16 + (lane & 15);
#pragma unroll
      for (int r = 0; r < 4; ++r) {
        const int m = m0 + wm * 32 + mf * 16 + (lane >> 4) * 4 + r;
        const float val = acc[mf][nf][r];
        if (n < 128)       Q[(size_t)m * DKn + n] = f2bf(val * 0.08838834764831845f);
        else if (n < 256)  K[(size_t)m * DKn + (n - 128)] = f2bf(val);
        else               Vt_l[n - 256][m - m0] = f2bf(val);  // transpose in LDS
      }
    }
  __syncthreads();
#pragma unroll
  for (int it = 0; it < 2; ++it) {
    const int ch = it * 512 + tid;   // 0..1023
    const int row = ch >> 3;
    const int g8 = ch & 7;
    u16x8 w = *reinterpret_cast<const u16x8*>(&Vt_l[row][g8 * 8]);
    *reinterpret_cast<u16x8*>(&VT[(size_t)bidx * DKn * Tn + (size_t)row * Tn + mb + g8 * 8]) = w;
  }
}

// ---------------- causal flash attention: XCD-pinned, KVBLK=64 ----------------
// 1-D grid 512; b = idx&7 pins each batch to one XCD (K/VT/Q L2-resident).
// x = idx>>3; t = x<32 ? 63-x : x-32 -> co-resident pair (idx, idx+256) sums to 63.
// 8 waves = 2 row-groups x 4-way KV split; 64 KV per iter (amortizes softmax chain).
__global__ __launch_bounds__(512, 4) void attn(
    const unsigned short* __restrict__ Qg,
    const unsigned short* __restrict__ Kg,
    const unsigned short* __restrict__ VTg,  // [8][128][2048]
    float* __restrict__ Out) {
  const int b = blockIdx.x & 7;            // XCD pin
  const int x = blockIdx.x >> 3;
  const int t = (x < 32) ? (63 - x) : (x - 32);
  const int q0 = t * 32;
  const int lane = threadIdx.x & 63;
  const int wid = threadIdx.x >> 6;        // 0..7
  const int rg = wid >> 2;                 // row group (16 rows)
  const int kp = wid & 3;                  // KV split index
  const int nb64 = (t + 2) >> 1;           // 64-wide KV blocks in causal range

  const unsigned short* Qb = Qg + (size_t)b * Tn * DKn;
  const unsigned short* Kb = Kg + (size_t)b * Tn * DKn;
  const unsigned short* Vt = VTg + (size_t)b * DKn * Tn;

  __shared__ __align__(16) unsigned short Pl[8][16][72];  // per-wave P roundtrip (18 KB)
  __shared__ float Ml[8][16][2];
  __shared__ float Om[4][16][132];                        // merge buffer (33 KB)

  bf16x8 qf[4];
  {
    const int qrow = q0 + rg * 16 + (lane & 15);
    const int c0 = (lane >> 4) * 8;
#pragma unroll
    for (int c = 0; c < 4; ++c)
      qf[c] = *reinterpret_cast<const bf16x8*>(&Qb[(size_t)qrow * DKn + c * 32 + c0]);
  }

  f32x4 o[8] = {};
  float mrow[4] = {-1e30f, -1e30f, -1e30f, -1e30f};
  float lrow[4] = {0.f, 0.f, 0.f, 0.f};
  const int rowbase = q0 + rg * 16 + (lane >> 4) * 4;
  const int c0 = (lane >> 4) * 8;

  for (int j = kp; j < nb64; j += 4) {
    const int s0j = j * 64;
    // S = Q K^T : 16 q-rows x 64 KV (4 nt tiles), K B-frags from XCD-local L2
    f32x4 sacc[4] = {};
#pragma unroll
    for (int nt = 0; nt < 4; ++nt) {
      const size_t krow = (size_t)(s0j + nt * 16 + (lane & 15)) * DKn;
#pragma unroll
      for (int kc = 0; kc < 4; ++kc) {
        bf16x8 kfv = *reinterpret_cast<const bf16x8*>(&Kb[krow + kc * 32 + c0]);
        sacc[nt] = __builtin_amdgcn_mfma_f32_16x16x32_bf16(qf[kc], kfv, sacc[nt], 0, 0, 0);
      }
    }

    // causal mask + online softmax (D layout: row=(lane>>4)*4+r = q, col=lane&15 = s)
    float pmax[4] = {-1e30f, -1e30f, -1e30f, -1e30f};
#pragma unroll
    for (int nt = 0; nt < 4; ++nt) {
      const int s = s0j + nt * 16 + (lane & 15);
#pragma unroll
      for (int r = 0; r < 4; ++r) {
        float vv = (s <= rowbase + r) ? sacc[nt][r] : -1e30f;
        sacc[nt][r] = vv;
        pmax[r] = fmaxf(pmax[r], vv);
      }
    }
#pragma unroll
    for (int r = 0; r < 4; ++r) {
      float m = pmax[r];
      m = fmaxf(m, __shfl_xor(m, 1));
      m = fmaxf(m, __shfl_xor(m, 2));
      m = fmaxf(m, __shfl_xor(m, 4));
      m = fmaxf(m, __shfl_xor(m, 8));
      float mnew = fmaxf(mrow[r], m);
      float f = __expf(mrow[r] - mnew);
      mrow[r] = mnew;
      float ps = 0.f;
#pragma unroll
      for (int nt = 0; nt < 4; ++nt) {
        float p = __expf(sacc[nt][r] - mnew);
        sacc[nt][r] = p;
        ps += p;
      }
      ps += __shfl_xor(ps, 1);
      ps += __shfl_xor(ps, 2);
      ps += __shfl_xor(ps, 4);
      ps += __shfl_xor(ps, 8);
      lrow[r] = lrow[r] * f + ps;
#pragma unroll
      for (int n = 0; n < 8; ++n) o[n][r] *= f;
    }

    // P: D layout -> A layout via wave-private LDS roundtrip
#pragma unroll
    for (int nt = 0; nt < 4; ++nt)
#pragma unroll
      for (int r = 0; r < 4; ++r)
        Pl[wid][(lane >> 4) * 4 + r][nt * 16 + (lane & 15)] = f2bf(sacc[nt][r]);
    bf16x8 pf[2];
#pragma unroll
    for (int kk = 0; kk < 2; ++kk)
      pf[kk] = *reinterpret_cast<const bf16x8*>(&Pl[wid][lane & 15][kk * 32 + c0]);

    // O += P V : V^T B-frags from XCD-local L2, 2 k-slices x 8 d-tiles
#pragma unroll
    for (int n = 0; n < 8; ++n) {
      const size_t vrow = (size_t)(n * 16 + (lane & 15)) * Tn + s0j;
#pragma unroll
      for (int kk = 0; kk < 2; ++kk) {
        bf16x8 vf = *reinterpret_cast<const bf16x8*>(&Vt[vrow + kk * 32 + c0]);
        o[n] = __builtin_amdgcn_mfma_f32_16x16x32_bf16(pf[kk], vf, o[n], 0, 0, 0);
      }
    }
  }

  // ---- merge 4 KV-partials per row group ----
  __syncthreads();
  for (int ph = 0; ph < 2; ++ph) {
    if (ph) __syncthreads();
    if (rg == ph) {
#pragma unroll
      for (int n = 0; n < 8; ++n)
#pragma unroll
        for (int r = 0; r < 4; ++r)
          Om[kp][(lane >> 4) * 4 + r][n * 16 + (lane & 15)] = o[n][r];
      if ((lane & 15) == 0)
#pragma unroll
        for (int r = 0; r < 4; ++r) {
          Ml[wid][(lane >> 4) * 4 + r][0] = mrow[r];
          Ml[wid][(lane >> 4) * 4 + r][1] = lrow[r];
        }
    }
    __syncthreads();
    if (rg == ph) {
      const int d = kp * 32 + (lane & 31);
      const int r0 = (lane >> 5) * 8;
#pragma unroll
      for (int rr = 0; rr < 8; ++rr) {
        int row = r0 + rr;
        float m0 = Ml[ph * 4 + 0][row][0], m1 = Ml[ph * 4 + 1][row][0];
        float m2 = Ml[ph * 4 + 2][row][0], m3 = Ml[ph * 4 + 3][row][0];
        float ms = fmaxf(fmaxf(m0, m1), fmaxf(m2, m3));
        float e0 = __expf(m0 - ms), e1 = __expf(m1 - ms);
        float e2 = __expf(m2 - ms), e3 = __expf(m3 - ms);
        float ls = Ml[ph * 4 + 0][row][1] * e0 + Ml[ph * 4 + 1][row][1] * e1 +
                   Ml[ph * 4 + 2][row][1] * e2 + Ml[ph * 4 + 3][row][1] * e3;
        float ov = Om[0][row][d] * e0 + Om[1][row][d] * e1 +
                   Om[2][row][d] * e2 + Om[3][row][d] * e3;
        Out[((size_t)b * Tn + q0 + ph * 16 + row) * DKn + d] = ov / ls;
      }
    }
  }
}

extern "C" void kernel_launch(void* const* d_in, const int* in_sizes, int n_in,
                              void* d_out, int out_size, void* d_ws, size_t ws_size,
                              hipStream_t stream) {
  const float* x  = (const float*)d_in[0];
  const float* Wq = (const float*)d_in[1];
  const float* Wk = (const float*)d_in[2];
  const float* Wv = (const float*)d_in[3];
  float* out = (float*)d_out;

  unsigned short* ws = (unsigned short*)d_ws;
  unsigned short* Wb  = ws;                                  // 384*1024
  unsigned short* Qw  = Wb + (size_t)384 * 1024;             // 16384*128
  unsigned short* Kw  = Qw + (size_t)16384 * 128;            // 16384*128
  unsigned short* VTw = Kw + (size_t)16384 * 128;            // 8*128*2048

  cvt_w<<<384, 256, 0, stream>>>(Wq, Wk, Wv, Wb);
  qkv_proj<<<256, 512, 0, stream>>>(x, Wb, Qw, Kw, VTw);
  attn<<<512, 512, 0, stream>>>(Qw, Kw, VTw, out);
}